// Round 2
// baseline (1861.760 us; speedup 1.0000x reference)
//
#include <hip/hip_runtime.h>

#define NE 500000      // edges
#define ND 50000       // nodes
#define DIMK 256       // embedding dim
#define H1 128
#define H2 64
#define GB 512         // persistent grid for the two GEMM passes
#define NT ((NE + 63) / 64)   // 7813 tiles of 64 edges
#define EPSBN 1e-5f

// fp16 storage for intermediates (10 mantissa bits; bf16's 8 was 2.05e-2 absmax)
static __device__ __forceinline__ unsigned short f2h(float f) {
  _Float16 h = (_Float16)f;
  return __builtin_bit_cast(unsigned short, h);
}
static __device__ __forceinline__ float h2f(unsigned short u) {
  return (float)__builtin_bit_cast(_Float16, u);
}

// c0[j] = b1[j] + step @ W1[768:800, j]   (edge-invariant part of layer 1)
__global__ void k_prep(const float* __restrict__ W1, const float* __restrict__ b1,
                       const float* __restrict__ step, float* __restrict__ c0) {
  const int j = threadIdx.x;
  if (j < H1) {
    float a = b1[j];
#pragma unroll
    for (int tt = 0; tt < 32; ++tt) a += step[tt] * W1[(768 + tt) * H1 + j];
    c0[j] = a;
  }
}

// Layer 1: x1 = relu(h_u@A + h_v@B + |h_u-h_v|@C + g*wg + c0), store fp16,
// accumulate per-feature sum/sumsq into per-block partials p1[256][GB].
__global__ __launch_bounds__(256, 2)
void k_layer1(const float* __restrict__ emb, const void* __restrict__ eidx_raw,
              const float* __restrict__ grad, const float* __restrict__ W1,
              const float* __restrict__ c0, unsigned short* __restrict__ x1,
              float* __restrict__ p1) {
  __shared__ __align__(16) float uT[16 * 68];   // [k][m], pad 68 keeps b128-aligned reads
  __shared__ __align__(16) float vT[16 * 68];
  __shared__ __align__(16) float wa[16 * 128];  // W1 rows [k0..k0+16) (h_u part)
  __shared__ __align__(16) float wb[16 * 128];  // (h_v part)
  __shared__ __align__(16) float wc[16 * 128];  // (diff part)
  __shared__ float s_sum[128], s_sq[128], s_wg[128], s_c0[128];
  __shared__ int s_src[64], s_dst[64];
  __shared__ float s_g[64];

  const int t = threadIdx.x;
  const int bid = blockIdx.x;
  if (t < 128) { s_sum[t] = 0.f; s_wg[t] = W1[800 * H1 + t]; s_c0[t] = c0[t]; }
  else         { s_sq[t - 128] = 0.f; }

  // int64-vs-int32 sniff: node ids < 50000, so int64 high words are 0.
  const unsigned* ew = (const unsigned*)eidx_raw;
  const bool is64 = ((ew[1] | ew[3] | ew[5] | ew[7]) == 0u);
  const int* e32 = (const int*)eidx_raw;
  const long long* e64 = (const long long*)eidx_raw;

  const int jg = t & 15, mg = t >> 4;
  const int j0 = jg * 4, m0 = mg * 4;
  const int mq = t >> 2, q = t & 3;
  const int lane = t & 63;

  for (int tile = bid; tile < NT; tile += gridDim.x) {
    const int base = tile * 64;
    __syncthreads();                      // protect s_g/s_src reuse across tiles
    if (t < 64) {
      int e = base + t; if (e >= NE) e = NE - 1;
      if (is64) { s_src[t] = (int)e64[e]; s_dst[t] = (int)e64[NE + e]; }
      else      { s_src[t] = e32[e];      s_dst[t] = e32[NE + e]; }
      s_g[t] = grad[e];
    }
    float acc[2][4][4];
#pragma unroll
    for (int h = 0; h < 2; ++h)
#pragma unroll
      for (int i = 0; i < 4; ++i)
#pragma unroll
        for (int c = 0; c < 4; ++c) acc[h][i][c] = 0.f;

#pragma unroll 1
    for (int kc = 0; kc < 16; ++kc) {
      const int k0 = kc * 16;
      __syncthreads();
      {
        const float* ur = emb + (size_t)s_src[mq] * DIMK + k0 + q * 4;
        const float* vr = emb + (size_t)s_dst[mq] * DIMK + k0 + q * 4;
        const float4 a = *(const float4*)ur;
        const float4 b = *(const float4*)vr;
        const int kb = q * 4;
        uT[(kb + 0) * 68 + mq] = a.x; uT[(kb + 1) * 68 + mq] = a.y;
        uT[(kb + 2) * 68 + mq] = a.z; uT[(kb + 3) * 68 + mq] = a.w;
        vT[(kb + 0) * 68 + mq] = b.x; vT[(kb + 1) * 68 + mq] = b.y;
        vT[(kb + 2) * 68 + mq] = b.z; vT[(kb + 3) * 68 + mq] = b.w;
      }
      {
        const int o = t * 8;
        const float4* pa = (const float4*)(W1 + (size_t)(k0)*H1 + o);
        const float4* pb = (const float4*)(W1 + (size_t)(256 + k0) * H1 + o);
        const float4* pc = (const float4*)(W1 + (size_t)(512 + k0) * H1 + o);
        *(float4*)&wa[o] = pa[0]; *(float4*)&wa[o + 4] = pa[1];
        *(float4*)&wb[o] = pb[0]; *(float4*)&wb[o + 4] = pb[1];
        *(float4*)&wc[o] = pc[0]; *(float4*)&wc[o + 4] = pc[1];
      }
      __syncthreads();
#pragma unroll 2
      for (int kk = 0; kk < 16; ++kk) {
        const float4 u4 = *(const float4*)&uT[kk * 68 + m0];
        const float4 v4 = *(const float4*)&vT[kk * 68 + m0];
        const float4 A0 = *(const float4*)&wa[kk * 128 + j0];
        const float4 A1 = *(const float4*)&wa[kk * 128 + j0 + 64];
        const float4 B0 = *(const float4*)&wb[kk * 128 + j0];
        const float4 B1 = *(const float4*)&wb[kk * 128 + j0 + 64];
        const float4 C0 = *(const float4*)&wc[kk * 128 + j0];
        const float4 C1 = *(const float4*)&wc[kk * 128 + j0 + 64];
        const float uu[4] = {u4.x, u4.y, u4.z, u4.w};
        const float vv[4] = {v4.x, v4.y, v4.z, v4.w};
        const float a0[4] = {A0.x, A0.y, A0.z, A0.w};
        const float a1[4] = {A1.x, A1.y, A1.z, A1.w};
        const float b0[4] = {B0.x, B0.y, B0.z, B0.w};
        const float b1a[4] = {B1.x, B1.y, B1.z, B1.w};
        const float cc0[4] = {C0.x, C0.y, C0.z, C0.w};
        const float cc1[4] = {C1.x, C1.y, C1.z, C1.w};
#pragma unroll
        for (int i = 0; i < 4; ++i) {
          const float du = fabsf(uu[i] - vv[i]);
#pragma unroll
          for (int c = 0; c < 4; ++c) {
            acc[0][i][c] += uu[i] * a0[c] + vv[i] * b0[c] + du * cc0[c];
            acc[1][i][c] += uu[i] * a1[c] + vv[i] * b1a[c] + du * cc1[c];
          }
        }
      }
    }
    // epilogue: grad term + c0, relu, fp16 store, per-feature stats
    float sx[2][4], sq2[2][4];
#pragma unroll
    for (int h = 0; h < 2; ++h)
#pragma unroll
      for (int c = 0; c < 4; ++c) { sx[h][c] = 0.f; sq2[h][c] = 0.f; }
#pragma unroll
    for (int i = 0; i < 4; ++i) {
      const int e = base + m0 + i;
      const bool valid = (e < NE);
      const float gi = s_g[m0 + i];
#pragma unroll
      for (int h = 0; h < 2; ++h) {
        const int jb = h * 64 + j0;
        float xs[4];
#pragma unroll
        for (int c = 0; c < 4; ++c) {
          float x = acc[h][i][c] + gi * s_wg[jb + c] + s_c0[jb + c];
          x = fmaxf(x, 0.f);
          if (!valid) x = 0.f;
          xs[c] = x; sx[h][c] += x; sq2[h][c] += x * x;
        }
        if (valid) {
          uint2 pk;
          pk.x = (unsigned)f2h(xs[0]) | ((unsigned)f2h(xs[1]) << 16);
          pk.y = (unsigned)f2h(xs[2]) | ((unsigned)f2h(xs[3]) << 16);
          *(uint2*)&x1[(size_t)e * H1 + jb] = pk;
        }
      }
    }
#pragma unroll
    for (int h = 0; h < 2; ++h)
#pragma unroll
      for (int c = 0; c < 4; ++c) {
        float a = sx[h][c];
        a += __shfl_xor(a, 16); a += __shfl_xor(a, 32);
        float b = sq2[h][c];
        b += __shfl_xor(b, 16); b += __shfl_xor(b, 32);
        if (lane < 16) {
          atomicAdd(&s_sum[h * 64 + j0 + c], a);
          atomicAdd(&s_sq[h * 64 + j0 + c], b);
        }
      }
  }
  __syncthreads();
  if (t < 128) p1[(size_t)t * GB + bid] = s_sum[t];
  else         p1[(size_t)t * GB + bid] = s_sq[t - 128];
}

// Finalize BN1 stats and fold into W2/b2: W2F = diag(s1)W2, b2F = b2 + t1@W2
__global__ void k_fin1(const float* __restrict__ p1, const float* __restrict__ g1,
                       const float* __restrict__ be1, const float* __restrict__ W2,
                       const float* __restrict__ b2, float* __restrict__ w2f,
                       float* __restrict__ b2f) {
  __shared__ float red[256];
  __shared__ float s1[128], t1[128];
  const int t = threadIdx.x;
  float s = 0.f;
  const float4* row = (const float4*)(p1 + (size_t)t * GB);
#pragma unroll 4
  for (int i = 0; i < GB / 4; ++i) { float4 v = row[i]; s += v.x + v.y + v.z + v.w; }
  red[t] = s;
  __syncthreads();
  if (t < 128) {
    const float inv = 1.0f / (float)NE;
    float mean = red[t] * inv;
    float var = red[128 + t] * inv - mean * mean;   // biased variance
    float sc = g1[t] * rsqrtf(var + EPSBN);
    s1[t] = sc;
    t1[t] = be1[t] - mean * sc;
  }
  __syncthreads();
  for (int i = t; i < H1 * H2; i += 256) w2f[i] = s1[i >> 6] * W2[i];
  if (t < 64) {
    float b = b2[t];
    for (int j = 0; j < 128; ++j) b += t1[j] * W2[j * 64 + t];
    b2f[t] = b;
  }
}

// Layer 2: x2 = relu(x1 @ W2F + b2F), fp16 store, stats into p2[128][GB]
__global__ __launch_bounds__(256, 2)
void k_layer2(const unsigned short* __restrict__ x1, const float* __restrict__ w2f,
              const float* __restrict__ b2f, unsigned short* __restrict__ x2,
              float* __restrict__ p2) {
  __shared__ __align__(16) unsigned short xT[128 * 68];  // fp16 [k][m]
  __shared__ __align__(16) float wl[128 * 64];
  __shared__ float s_sum[64], s_sq[64], s_b[64];
  const int t = threadIdx.x, bid = blockIdx.x;
  for (int i = t; i < (128 * 64) / 4; i += 256)
    ((float4*)wl)[i] = ((const float4*)w2f)[i];
  if (t < 64) { s_sum[t] = 0.f; s_sq[t] = 0.f; s_b[t] = b2f[t]; }
  const int jg = t & 15, mg = t >> 4, j0 = jg * 4, m0 = mg * 4;
  const int mq = t >> 2, q = t & 3;
  const int lane = t & 63;

  for (int tile = bid; tile < NT; tile += gridDim.x) {
    const int base = tile * 64;
    __syncthreads();
    {
      int e = base + mq; if (e >= NE) e = NE - 1;
      const uint4* r = (const uint4*)(x1 + (size_t)e * H1 + q * 32);
#pragma unroll
      for (int i = 0; i < 4; ++i) {
        const uint4 u = r[i];
        const int kb = q * 32 + i * 8;
        xT[(kb + 0) * 68 + mq] = (unsigned short)(u.x & 0xffff);
        xT[(kb + 1) * 68 + mq] = (unsigned short)(u.x >> 16);
        xT[(kb + 2) * 68 + mq] = (unsigned short)(u.y & 0xffff);
        xT[(kb + 3) * 68 + mq] = (unsigned short)(u.y >> 16);
        xT[(kb + 4) * 68 + mq] = (unsigned short)(u.z & 0xffff);
        xT[(kb + 5) * 68 + mq] = (unsigned short)(u.z >> 16);
        xT[(kb + 6) * 68 + mq] = (unsigned short)(u.w & 0xffff);
        xT[(kb + 7) * 68 + mq] = (unsigned short)(u.w >> 16);
      }
    }
    __syncthreads();
    float acc[4][4];
#pragma unroll
    for (int i = 0; i < 4; ++i)
#pragma unroll
      for (int c = 0; c < 4; ++c) acc[i][c] = 0.f;
#pragma unroll 4
    for (int kk = 0; kk < 128; ++kk) {
      const uint2 xw = *(const uint2*)&xT[kk * 68 + m0];
      const float4 w4 = *(const float4*)&wl[kk * 64 + j0];
      const float xm[4] = {h2f(xw.x & 0xffff), h2f(xw.x >> 16),
                           h2f(xw.y & 0xffff), h2f(xw.y >> 16)};
      const float wc4[4] = {w4.x, w4.y, w4.z, w4.w};
#pragma unroll
      for (int i = 0; i < 4; ++i)
#pragma unroll
        for (int c = 0; c < 4; ++c) acc[i][c] += xm[i] * wc4[c];
    }
    float sx[4] = {0, 0, 0, 0}, sq2[4] = {0, 0, 0, 0};
#pragma unroll
    for (int i = 0; i < 4; ++i) {
      const int e = base + m0 + i;
      const bool valid = (e < NE);
      float xs[4];
#pragma unroll
      for (int c = 0; c < 4; ++c) {
        float x = acc[i][c] + s_b[j0 + c];
        x = fmaxf(x, 0.f);
        if (!valid) x = 0.f;
        xs[c] = x; sx[c] += x; sq2[c] += x * x;
      }
      if (valid) {
        uint2 pk;
        pk.x = (unsigned)f2h(xs[0]) | ((unsigned)f2h(xs[1]) << 16);
        pk.y = (unsigned)f2h(xs[2]) | ((unsigned)f2h(xs[3]) << 16);
        *(uint2*)&x2[(size_t)e * H2 + j0] = pk;
      }
    }
#pragma unroll
    for (int c = 0; c < 4; ++c) {
      float a = sx[c]; a += __shfl_xor(a, 16); a += __shfl_xor(a, 32);
      float b = sq2[c]; b += __shfl_xor(b, 16); b += __shfl_xor(b, 32);
      if (lane < 16) { atomicAdd(&s_sum[j0 + c], a); atomicAdd(&s_sq[j0 + c], b); }
    }
  }
  __syncthreads();
  if (t < 64)       p2[(size_t)t * GB + bid] = s_sum[t];
  else if (t < 128) p2[(size_t)t * GB + bid] = s_sq[t - 64];
}

// Finalize BN2 and fold into W3/b3
__global__ void k_fin2(const float* __restrict__ p2, const float* __restrict__ g2,
                       const float* __restrict__ be2, const float* __restrict__ W3,
                       const float* __restrict__ b3, float* __restrict__ w3f,
                       float* __restrict__ b3f) {
  __shared__ float red[128];
  __shared__ float tp[64];
  const int t = threadIdx.x;
  float s = 0.f;
  const float4* row = (const float4*)(p2 + (size_t)t * GB);
#pragma unroll 4
  for (int i = 0; i < GB / 4; ++i) { float4 v = row[i]; s += v.x + v.y + v.z + v.w; }
  red[t] = s;
  __syncthreads();
  if (t < 64) {
    const float inv = 1.0f / (float)NE;
    float mean = red[t] * inv;
    float var = red[64 + t] * inv - mean * mean;
    float sc = g2[t] * rsqrtf(var + EPSBN);
    float tt = be2[t] - mean * sc;
    w3f[t] = sc * W3[t];
    tp[t] = tt * W3[t];
  }
  __syncthreads();
  if (t == 0) {
    float b = b3[0];
    for (int j = 0; j < 64; ++j) b += tp[j];
    b3f[0] = b;
  }
}

// out = tanh(x2 @ w3f + b3f); 4 lanes per edge, shuffle-reduce
__global__ __launch_bounds__(256)
void k_out(const unsigned short* __restrict__ x2, const float* __restrict__ w3f,
           const float* __restrict__ b3f, float* __restrict__ out) {
  __shared__ float s_w[64];
  __shared__ float s_b;
  const int t = threadIdx.x;
  if (t < 64) s_w[t] = w3f[t];
  if (t == 0) s_b = b3f[0];
  __syncthreads();
  const int gid = blockIdx.x * 256 + t;
  const int e = gid >> 2, p = gid & 3;
  if (e < NE) {
    const uint4* r = (const uint4*)(x2 + (size_t)e * H2 + p * 16);
    float s = 0.f;
#pragma unroll
    for (int i = 0; i < 2; ++i) {
      const uint4 u = r[i];
      const int jb = p * 16 + i * 8;
      s += h2f(u.x & 0xffff) * s_w[jb + 0] + h2f(u.x >> 16) * s_w[jb + 1];
      s += h2f(u.y & 0xffff) * s_w[jb + 2] + h2f(u.y >> 16) * s_w[jb + 3];
      s += h2f(u.z & 0xffff) * s_w[jb + 4] + h2f(u.z >> 16) * s_w[jb + 5];
      s += h2f(u.w & 0xffff) * s_w[jb + 6] + h2f(u.w >> 16) * s_w[jb + 7];
    }
    s += __shfl_xor(s, 1);
    s += __shfl_xor(s, 2);
    if (p == 0) out[e] = tanhf(s + s_b);
  }
}

extern "C" void kernel_launch(void* const* d_in, const int* in_sizes, int n_in,
                              void* d_out, int out_size, void* d_ws, size_t ws_size,
                              hipStream_t stream) {
  const float* emb  = (const float*)d_in[0];
  const float* grad = (const float*)d_in[1];
  const float* step = (const float*)d_in[2];
  const float* W1   = (const float*)d_in[3];
  const float* b1   = (const float*)d_in[4];
  const float* g1   = (const float*)d_in[5];
  const float* be1  = (const float*)d_in[6];
  const float* W2   = (const float*)d_in[7];
  const float* b2   = (const float*)d_in[8];
  const float* g2   = (const float*)d_in[9];
  const float* be2  = (const float*)d_in[10];
  const float* W3   = (const float*)d_in[11];
  const float* b3   = (const float*)d_in[12];
  const void*  eidx = (const void*)d_in[13];
  float* out = (float*)d_out;

  char* ws = (char*)d_ws;
  unsigned short* x1 = (unsigned short*)(ws + 0);              // 128,000,000 B
  unsigned short* x2 = (unsigned short*)(ws + 128000000LL);    //  64,000,000 B
  float* p1  = (float*)(ws + 192000000LL);                     //     524,288 B
  float* p2  = (float*)(ws + 192524288LL);                     //     262,144 B
  float* c0  = (float*)(ws + 192786432LL);                     //         512 B
  float* w2f = (float*)(ws + 192786944LL);                     //      32,768 B
  float* b2f = (float*)(ws + 192819712LL);                     //         256 B
  float* w3f = (float*)(ws + 192819968LL);                     //         256 B
  float* b3f = (float*)(ws + 192820224LL);                     //          16 B

  k_prep  <<<1,   256, 0, stream>>>(W1, b1, step, c0);
  k_layer1<<<GB,  256, 0, stream>>>(emb, eidx, grad, W1, c0, x1, p1);
  k_fin1  <<<1,   256, 0, stream>>>(p1, g1, be1, W2, b2, w2f, b2f);
  k_layer2<<<GB,  256, 0, stream>>>(x1, w2f, b2f, x2, p2);
  k_fin2  <<<1,   128, 0, stream>>>(p2, g2, be2, W3, b3, w3f, b3f);
  k_out   <<<(NE * 4 + 255) / 256, 256, 0, stream>>>(x2, w3f, b3f, out);
}

// Round 3
// 522.598 us; speedup vs baseline: 3.5625x; 3.5625x over previous
//
#include <hip/hip_runtime.h>

#define NE 500000      // edges
#define DIMK 256       // embedding dim
#define H1 128
#define H2 64
#define EPSBN 1e-5f
#define GRID1 512
#define NT1 1954                 // tiles of 256 edges
#define NJOBS1 (NT1 * 4)         // layer1: 4 N-quarters of 32 cols
#define NJOBS2 NT1

typedef _Float16 half8 __attribute__((ext_vector_type(8)));
typedef float f32x4 __attribute__((ext_vector_type(4)));
typedef unsigned short ushort8 __attribute__((ext_vector_type(8)));

static __device__ __forceinline__ half8 habs8(half8 x) {
  ushort8 u = __builtin_bit_cast(ushort8, x);
  u &= (unsigned short)0x7FFF;
  return __builtin_bit_cast(half8, u);
}
static __device__ __forceinline__ float h2f(unsigned int u) {
  return (float)__builtin_bit_cast(_Float16, (unsigned short)(u & 0xffff));
}

// c0[j] = b1[j] + step @ W1[768:800, j]
__global__ void k_prep(const float* __restrict__ W1, const float* __restrict__ b1,
                       const float* __restrict__ step, float* __restrict__ c0) {
  const int j = threadIdx.x;
  if (j < H1) {
    float a = b1[j];
#pragma unroll
    for (int tt = 0; tt < 32; ++tt) a += step[tt] * W1[(768 + tt) * H1 + j];
    c0[j] = a;
  }
}

// fp32 emb -> fp16 copy (12.8M elems, 8/thread, exact grid)
__global__ void k_prep16(const float* __restrict__ emb, _Float16* __restrict__ embh) {
  const int i = (blockIdx.x * 256 + threadIdx.x) * 8;
  const float4 a = *(const float4*)(emb + i);
  const float4 b = *(const float4*)(emb + i + 4);
  half8 h;
  h[0] = (_Float16)a.x; h[1] = (_Float16)a.y; h[2] = (_Float16)a.z; h[3] = (_Float16)a.w;
  h[4] = (_Float16)b.x; h[5] = (_Float16)b.y; h[6] = (_Float16)b.z; h[7] = (_Float16)b.w;
  *(half8*)(embh + i) = h;
}

// Layer 1 via MFMA fp16: x1 = relu([u|v|du] @ W1[0:768] + g*wg + c0)
// Block handles N-quarter nq (32 cols), tiles of 256 edges; B resident in LDS
// in fragment order; A fragments gathered directly from embh (16B/lane).
__global__ __launch_bounds__(256, 2)
void k_layer1(const _Float16* __restrict__ embh, const void* __restrict__ eidx_raw,
              const float* __restrict__ grad, const float* __restrict__ W1,
              const float* __restrict__ c0, _Float16* __restrict__ x1,
              float* __restrict__ p1) {
  __shared__ __align__(16) _Float16 b_lds[24576];   // 3 segs x 8 ksteps x 2 coltiles, frag order
  __shared__ int s_src[256], s_dst[256];
  __shared__ float s_g[256];
  __shared__ float s_wg[32], s_c0[32], s_sum[32], s_sq[32];

  const int t = threadIdx.x, bid = blockIdx.x;
  const int nq = bid & 3;
  const int w = t >> 6, lane = t & 63, quad = lane >> 4, m15 = lane & 15;

  // stage B fragments once: b_lds[((s*16+kk*2+c)*64+lane)*8+j] = W1[s*256+kk*32+(lane>>4)*8+j][nq*32+c*16+(lane&15)]
  for (int i = t; i < 24576; i += 256) {
    const int j = i & 7, li = (i >> 3) & 63, f = i >> 9;
    const int c = f & 1, kk = (f >> 1) & 7, s = f >> 4;
    const int row = s * 256 + kk * 32 + (li >> 4) * 8 + j;
    const int col = nq * 32 + c * 16 + (li & 15);
    b_lds[i] = (_Float16)W1[row * H1 + col];
  }
  if (t < 32) {
    s_wg[t] = W1[800 * H1 + nq * 32 + t];
    s_c0[t] = c0[nq * 32 + t];
    s_sum[t] = 0.f; s_sq[t] = 0.f;
  }

  const unsigned* ew = (const unsigned*)eidx_raw;
  const bool is64 = ((ew[1] | ew[3] | ew[5] | ew[7]) == 0u);
  const int* e32 = (const int*)eidx_raw;
  const long long* e64 = (const long long*)eidx_raw;

  float st_s[2] = {0.f, 0.f}, st_q[2] = {0.f, 0.f};

  for (int job = bid; job < NJOBS1; job += GRID1) {   // job & 3 == nq (512 % 4 == 0)
    const int tile = job >> 2;
    const int base = tile * 256;
    __syncthreads();
    {
      int e = base + t; if (e >= NE) e = NE - 1;
      if (is64) { s_src[t] = (int)e64[e]; s_dst[t] = (int)e64[NE + e]; }
      else      { s_src[t] = e32[e];      s_dst[t] = e32[NE + e]; }
      s_g[t] = grad[e];
    }
    __syncthreads();

    const int r0 = w * 64 + m15;
    const _Float16* pu[4];
    const _Float16* pv[4];
#pragma unroll
    for (int r = 0; r < 4; ++r) {
      pu[r] = embh + (size_t)s_src[r0 + r * 16] * DIMK + quad * 8;
      pv[r] = embh + (size_t)s_dst[r0 + r * 16] * DIMK + quad * 8;
    }
    f32x4 acc[4][2];
#pragma unroll
    for (int r = 0; r < 4; ++r)
#pragma unroll
      for (int c = 0; c < 2; ++c) acc[r][c] = (f32x4)0.f;

    const half8* bp = (const half8*)b_lds;
#pragma unroll 2
    for (int kk = 0; kk < 8; ++kk) {
      half8 u[4], v[4], d[4];
#pragma unroll
      for (int r = 0; r < 4; ++r) {
        u[r] = *(const half8*)(pu[r] + kk * 32);
        v[r] = *(const half8*)(pv[r] + kk * 32);
      }
#pragma unroll
      for (int r = 0; r < 4; ++r) d[r] = habs8(u[r] - v[r]);
#pragma unroll
      for (int c = 0; c < 2; ++c) {
        const half8 bu = bp[(0 * 16 + kk * 2 + c) * 64 + lane];
        const half8 bv = bp[(1 * 16 + kk * 2 + c) * 64 + lane];
        const half8 bd = bp[(2 * 16 + kk * 2 + c) * 64 + lane];
#pragma unroll
        for (int r = 0; r < 4; ++r) {
          acc[r][c] = __builtin_amdgcn_mfma_f32_16x16x32_f16(u[r], bu, acc[r][c], 0, 0, 0);
          acc[r][c] = __builtin_amdgcn_mfma_f32_16x16x32_f16(v[r], bv, acc[r][c], 0, 0, 0);
          acc[r][c] = __builtin_amdgcn_mfma_f32_16x16x32_f16(d[r], bd, acc[r][c], 0, 0, 0);
        }
      }
    }
    // epilogue: D layout col=lane&15, row=quad*4+reg
#pragma unroll
    for (int r = 0; r < 4; ++r) {
      const int erow = w * 64 + r * 16 + quad * 4;
#pragma unroll
      for (int c = 0; c < 2; ++c) {
        const int colL = c * 16 + m15;
        const float wgv = s_wg[colL], c0v = s_c0[colL];
#pragma unroll
        for (int reg = 0; reg < 4; ++reg) {
          const int e = base + erow + reg;
          float x = acc[r][c][reg] + s_g[erow + reg] * wgv + c0v;
          x = fmaxf(x, 0.f);
          if (e >= NE) x = 0.f;
          st_s[c] += x; st_q[c] += x * x;
          if (e < NE) x1[(size_t)e * H1 + nq * 32 + colL] = (_Float16)x;
        }
      }
    }
  }
  __syncthreads();
#pragma unroll
  for (int c = 0; c < 2; ++c) {
    float a = st_s[c]; a += __shfl_xor(a, 16); a += __shfl_xor(a, 32);
    float b = st_q[c]; b += __shfl_xor(b, 16); b += __shfl_xor(b, 32);
    if (lane < 16) { atomicAdd(&s_sum[c * 16 + m15], a); atomicAdd(&s_sq[c * 16 + m15], b); }
  }
  __syncthreads();
  if (t < 32) {
    const int colG = nq * 32 + t;
    p1[colG * 128 + (bid >> 2)] = s_sum[t];
    p1[128 * 128 + colG * 128 + (bid >> 2)] = s_sq[t];
  }
}

// Finalize BN1 stats, fold into W2/b2 (fp32 row-major out)
__global__ void k_fin1(const float* __restrict__ p1, const float* __restrict__ g1,
                       const float* __restrict__ be1, const float* __restrict__ W2,
                       const float* __restrict__ b2, float* __restrict__ w2f,
                       float* __restrict__ b2f) {
  __shared__ float s1[128], t1[128];
  const int t = threadIdx.x;
  if (t < 128) {
    float s = 0.f, q = 0.f;
    const float4* rs = (const float4*)(p1 + t * 128);
    const float4* rq = (const float4*)(p1 + 128 * 128 + t * 128);
#pragma unroll 4
    for (int i = 0; i < 32; ++i) {
      float4 a = rs[i]; s += a.x + a.y + a.z + a.w;
      float4 b = rq[i]; q += b.x + b.y + b.z + b.w;
    }
    const float inv = 1.0f / (float)NE;
    float mean = s * inv;
    float var = q * inv - mean * mean;
    float sc = g1[t] * rsqrtf(var + EPSBN);
    s1[t] = sc; t1[t] = be1[t] - mean * sc;
  }
  __syncthreads();
  for (int i = t; i < H1 * H2; i += 256) w2f[i] = s1[i >> 6] * W2[i];
  if (t < 64) {
    float b = b2[t];
    for (int j = 0; j < 128; ++j) b += t1[j] * W2[j * 64 + t];
    b2f[t] = b;
  }
}

// Layer 2 via MFMA: x2 = relu(x1 @ W2F + b2F), B (16KB) resident in LDS
__global__ __launch_bounds__(256, 2)
void k_layer2(const _Float16* __restrict__ x1, const float* __restrict__ w2f,
              const float* __restrict__ b2f, _Float16* __restrict__ x2,
              float* __restrict__ p2) {
  __shared__ __align__(16) _Float16 b_lds[8192];  // 4 ksteps x 4 coltiles frag order
  __shared__ float s_b[64], s_sum[64], s_sq[64];
  const int t = threadIdx.x, bid = blockIdx.x;
  const int w = t >> 6, lane = t & 63, quad = lane >> 4, m15 = lane & 15;

  for (int i = t; i < 8192; i += 256) {
    const int j = i & 7, li = (i >> 3) & 63, f = i >> 9;
    const int c = f & 3, kk = f >> 2;
    const int row = kk * 32 + (li >> 4) * 8 + j;
    const int col = c * 16 + (li & 15);
    b_lds[i] = (_Float16)w2f[row * H2 + col];
  }
  if (t < 64) { s_b[t] = b2f[t]; s_sum[t] = 0.f; s_sq[t] = 0.f; }
  __syncthreads();

  float st_s[4] = {0, 0, 0, 0}, st_q[4] = {0, 0, 0, 0};
  const half8* bp = (const half8*)b_lds;

  for (int job = bid; job < NJOBS2; job += GRID1) {
    const int base = job * 256;
    const _Float16* pa[4];
#pragma unroll
    for (int r = 0; r < 4; ++r) {
      int e = base + w * 64 + r * 16 + m15; if (e >= NE) e = NE - 1;
      pa[r] = x1 + (size_t)e * H1 + quad * 8;
    }
    f32x4 acc[4][4];
#pragma unroll
    for (int r = 0; r < 4; ++r)
#pragma unroll
      for (int c = 0; c < 4; ++c) acc[r][c] = (f32x4)0.f;

#pragma unroll
    for (int kk = 0; kk < 4; ++kk) {
      half8 a[4];
#pragma unroll
      for (int r = 0; r < 4; ++r) a[r] = *(const half8*)(pa[r] + kk * 32);
#pragma unroll
      for (int c = 0; c < 4; ++c) {
        const half8 bf = bp[(kk * 4 + c) * 64 + lane];
#pragma unroll
        for (int r = 0; r < 4; ++r)
          acc[r][c] = __builtin_amdgcn_mfma_f32_16x16x32_f16(a[r], bf, acc[r][c], 0, 0, 0);
      }
    }
#pragma unroll
    for (int r = 0; r < 4; ++r) {
      const int erow = w * 64 + r * 16 + quad * 4;
#pragma unroll
      for (int c = 0; c < 4; ++c) {
        const int colL = c * 16 + m15;
        const float bv = s_b[colL];
#pragma unroll
        for (int reg = 0; reg < 4; ++reg) {
          const int e = base + erow + reg;
          float x = acc[r][c][reg] + bv;
          x = fmaxf(x, 0.f);
          if (e >= NE) x = 0.f;
          st_s[c] += x; st_q[c] += x * x;
          if (e < NE) x2[(size_t)e * H2 + colL] = (_Float16)x;
        }
      }
    }
  }
  __syncthreads();
#pragma unroll
  for (int c = 0; c < 4; ++c) {
    float a = st_s[c]; a += __shfl_xor(a, 16); a += __shfl_xor(a, 32);
    float b = st_q[c]; b += __shfl_xor(b, 16); b += __shfl_xor(b, 32);
    if (lane < 16) { atomicAdd(&s_sum[c * 16 + m15], a); atomicAdd(&s_sq[c * 16 + m15], b); }
  }
  __syncthreads();
  if (t < 64) {
    p2[t * 512 + bid] = s_sum[t];
    p2[64 * 512 + t * 512 + bid] = s_sq[t];
  }
}

// Finalize BN2, fold into W3/b3
__global__ void k_fin2(const float* __restrict__ p2, const float* __restrict__ g2,
                       const float* __restrict__ be2, const float* __restrict__ W3,
                       const float* __restrict__ b3, float* __restrict__ w3f,
                       float* __restrict__ b3f) {
  __shared__ float tp[64];
  const int t = threadIdx.x;
  if (t < 64) {
    float s = 0.f, q = 0.f;
    const float4* rs = (const float4*)(p2 + t * 512);
    const float4* rq = (const float4*)(p2 + 64 * 512 + t * 512);
#pragma unroll 4
    for (int i = 0; i < 128; ++i) {
      float4 a = rs[i]; s += a.x + a.y + a.z + a.w;
      float4 b = rq[i]; q += b.x + b.y + b.z + b.w;
    }
    const float inv = 1.0f / (float)NE;
    float mean = s * inv;
    float var = q * inv - mean * mean;
    float sc = g2[t] * rsqrtf(var + EPSBN);
    float tt = be2[t] - mean * sc;
    w3f[t] = sc * W3[t];
    tp[t] = tt * W3[t];
  }
  __syncthreads();
  if (t == 0) {
    float b = b3[0];
    for (int j = 0; j < 64; ++j) b += tp[j];
    b3f[0] = b;
  }
}

// out = tanh(x2 @ w3f + b3f); 4 lanes per edge
__global__ __launch_bounds__(256)
void k_out(const unsigned short* __restrict__ x2, const float* __restrict__ w3f,
           const float* __restrict__ b3f, float* __restrict__ out) {
  __shared__ float s_w[64];
  __shared__ float s_b;
  const int t = threadIdx.x;
  if (t < 64) s_w[t] = w3f[t];
  if (t == 0) s_b = b3f[0];
  __syncthreads();
  const int gid = blockIdx.x * 256 + t;
  const int e = gid >> 2, p = gid & 3;
  if (e < NE) {
    const uint4* r = (const uint4*)(x2 + (size_t)e * H2 + p * 16);
    float s = 0.f;
#pragma unroll
    for (int i = 0; i < 2; ++i) {
      const uint4 u = r[i];
      const int jb = p * 16 + i * 8;
      s += h2f(u.x) * s_w[jb + 0] + h2f(u.x >> 16) * s_w[jb + 1];
      s += h2f(u.y) * s_w[jb + 2] + h2f(u.y >> 16) * s_w[jb + 3];
      s += h2f(u.z) * s_w[jb + 4] + h2f(u.z >> 16) * s_w[jb + 5];
      s += h2f(u.w) * s_w[jb + 6] + h2f(u.w >> 16) * s_w[jb + 7];
    }
    s += __shfl_xor(s, 1);
    s += __shfl_xor(s, 2);
    if (p == 0) out[e] = tanhf(s + s_b);
  }
}

extern "C" void kernel_launch(void* const* d_in, const int* in_sizes, int n_in,
                              void* d_out, int out_size, void* d_ws, size_t ws_size,
                              hipStream_t stream) {
  const float* emb  = (const float*)d_in[0];
  const float* grad = (const float*)d_in[1];
  const float* step = (const float*)d_in[2];
  const float* W1   = (const float*)d_in[3];
  const float* b1   = (const float*)d_in[4];
  const float* g1   = (const float*)d_in[5];
  const float* be1  = (const float*)d_in[6];
  const float* W2   = (const float*)d_in[7];
  const float* b2   = (const float*)d_in[8];
  const float* g2   = (const float*)d_in[9];
  const float* be2  = (const float*)d_in[10];
  const float* W3   = (const float*)d_in[11];
  const float* b3   = (const float*)d_in[12];
  const void*  eidx = (const void*)d_in[13];
  float* out = (float*)d_out;

  char* ws = (char*)d_ws;
  // region A: embh (25.6MB) for layer1, then x2 (64MB) overwrites after layer1
  _Float16* embh = (_Float16*)(ws + 0);
  _Float16* x2   = (_Float16*)(ws + 0);
  _Float16* x1   = (_Float16*)(ws + 64000000LL);   // 128,000,000 B
  float* p1  = (float*)(ws + 192000000LL);         // 131,072 B
  float* p2  = (float*)(ws + 192131072LL);         // 262,144 B
  float* c0  = (float*)(ws + 192393216LL);         // 512 B
  float* w2f = (float*)(ws + 192393728LL);         // 32,768 B
  float* b2f = (float*)(ws + 192426496LL);         // 256 B
  float* w3f = (float*)(ws + 192426752LL);         // 256 B
  float* b3f = (float*)(ws + 192427008LL);         // 16 B

  k_prep  <<<1,    256, 0, stream>>>(W1, b1, step, c0);
  k_prep16<<<6250, 256, 0, stream>>>(emb, embh);
  k_layer1<<<GRID1,256, 0, stream>>>(embh, eidx, grad, W1, c0, x1, p1);
  k_fin1  <<<1,    256, 0, stream>>>(p1, g1, be1, W2, b2, w2f, b2f);
  k_layer2<<<GRID1,256, 0, stream>>>(x1, w2f, b2f, x2, p2);
  k_fin2  <<<1,    128, 0, stream>>>(p2, g2, be2, W3, b3, w3f, b3f);
  k_out   <<<7813, 256, 0, stream>>>((const unsigned short*)x2, w3f, b3f, out);
}

// Round 4
// 383.842 us; speedup vs baseline: 4.8503x; 1.3615x over previous
//
#include <hip/hip_runtime.h>

#define NE 500000      // edges
#define DIMK 256       // embedding dim
#define H1 128
#define H2 64
#define EPSBN 1e-5f
#define GRID1 512
#define NT1 1954                 // tiles of 256 edges
#define NJOBS2 NT1

typedef _Float16 half8 __attribute__((ext_vector_type(8)));
typedef float f32x4 __attribute__((ext_vector_type(4)));
typedef unsigned short ushort8 __attribute__((ext_vector_type(8)));

static __device__ __forceinline__ half8 habs8(half8 x) {
  ushort8 u = __builtin_bit_cast(ushort8, x);
  u &= (unsigned short)0x7FFF;
  return __builtin_bit_cast(half8, u);
}
static __device__ __forceinline__ float h2f(unsigned int u) {
  return (float)__builtin_bit_cast(_Float16, (unsigned short)(u & 0xffff));
}

// c0[j] = b1[j] + step @ W1[768:800, j]
__global__ void k_prep(const float* __restrict__ W1, const float* __restrict__ b1,
                       const float* __restrict__ step, float* __restrict__ c0) {
  const int j = threadIdx.x;
  if (j < H1) {
    float a = b1[j];
#pragma unroll
    for (int tt = 0; tt < 32; ++tt) a += step[tt] * W1[(768 + tt) * H1 + j];
    c0[j] = a;
  }
}

// fp32 emb -> fp16 copy (12.8M elems, 8/thread, exact grid)
__global__ void k_prep16(const float* __restrict__ emb, _Float16* __restrict__ embh) {
  const int i = (blockIdx.x * 256 + threadIdx.x) * 8;
  const float4 a = *(const float4*)(emb + i);
  const float4 b = *(const float4*)(emb + i + 4);
  half8 h;
  h[0] = (_Float16)a.x; h[1] = (_Float16)a.y; h[2] = (_Float16)a.z; h[3] = (_Float16)a.w;
  h[4] = (_Float16)b.x; h[5] = (_Float16)b.y; h[6] = (_Float16)b.z; h[7] = (_Float16)b.w;
  *(half8*)(embh + i) = h;
}

// Build fragment-ordered B for layer1: bfrag[(s*64+kc*8+c)*64*8 + lane*8 + j]
//   = W1[s*256 + kc*32 + (lane>>4)*8 + j][c*16 + (lane&15)]   (fp16)
// 48 blocks x 256: thread g covers (f = g>>6, lane = g&63), writes 8 halves.
__global__ void k_prepB(const float* __restrict__ W1, _Float16* __restrict__ bfrag) {
  const int g = blockIdx.x * 256 + threadIdx.x;
  const int lane = g & 63, f = g >> 6;
  const int c = f & 7, kc = (f >> 3) & 7, s = f >> 6;
  const int row0 = s * 256 + kc * 32 + (lane >> 4) * 8;
  const int col = c * 16 + (lane & 15);
  half8 h;
#pragma unroll
  for (int j = 0; j < 8; ++j) h[j] = (_Float16)W1[(row0 + j) * H1 + col];
  *(half8*)(bfrag + (size_t)g * 8) = h;
}

// Layer 1 via MFMA fp16, FULL 128-col output per 256-edge tile.
// A fragments gathered directly from embh (16B/lane); B fragments streamed
// from the fragment-ordered global array (coalesced dwordx4, L2-resident).
__global__ __launch_bounds__(256, 2)
void k_layer1(const _Float16* __restrict__ embh, const void* __restrict__ eidx_raw,
              const float* __restrict__ grad, const float* __restrict__ W1,
              const float* __restrict__ c0, const _Float16* __restrict__ bfrag,
              _Float16* __restrict__ x1, float* __restrict__ p1) {
  __shared__ int s_src[256], s_dst[256];
  __shared__ float s_g[256];
  __shared__ float s_wg[128], s_c0[128], s_sum[128], s_sq[128];

  const int t = threadIdx.x, bid = blockIdx.x;
  const int w = t >> 6, lane = t & 63, quad = lane >> 4, m15 = lane & 15;

  if (t < 128) {
    s_wg[t] = W1[800 * H1 + t];
    s_c0[t] = c0[t];
    s_sum[t] = 0.f; s_sq[t] = 0.f;
  }

  const unsigned* ew = (const unsigned*)eidx_raw;
  const bool is64 = ((ew[1] | ew[3] | ew[5] | ew[7]) == 0u);
  const int* e32 = (const int*)eidx_raw;
  const long long* e64 = (const long long*)eidx_raw;

  float st_s[8] = {0, 0, 0, 0, 0, 0, 0, 0}, st_q[8] = {0, 0, 0, 0, 0, 0, 0, 0};
  const half8* bp = (const half8*)bfrag;

  for (int tile = bid; tile < NT1; tile += GRID1) {
    const int base = tile * 256;
    __syncthreads();
    {
      int e = base + t; if (e >= NE) e = NE - 1;
      if (is64) { s_src[t] = (int)e64[e]; s_dst[t] = (int)e64[NE + e]; }
      else      { s_src[t] = e32[e];      s_dst[t] = e32[NE + e]; }
      s_g[t] = grad[e];
    }
    __syncthreads();

    const int r0 = w * 64 + m15;
    const _Float16* pu[4];
    const _Float16* pv[4];
#pragma unroll
    for (int r = 0; r < 4; ++r) {
      pu[r] = embh + (size_t)s_src[r0 + r * 16] * DIMK + quad * 8;
      pv[r] = embh + (size_t)s_dst[r0 + r * 16] * DIMK + quad * 8;
    }
    f32x4 acc[4][8];
#pragma unroll
    for (int r = 0; r < 4; ++r)
#pragma unroll
      for (int c = 0; c < 8; ++c) acc[r][c] = (f32x4)0.f;

#pragma unroll 1
    for (int kc = 0; kc < 8; ++kc) {
      half8 u[4], v[4], d[4];
#pragma unroll
      for (int r = 0; r < 4; ++r) {
        u[r] = *(const half8*)(pu[r] + kc * 32);
        v[r] = *(const half8*)(pv[r] + kc * 32);
      }
#pragma unroll
      for (int r = 0; r < 4; ++r) d[r] = habs8(u[r] - v[r]);

      // B-frag index: f = s*64 + kc*8 + c
      half8 bu = bp[(kc * 8 + 0) * 64 + lane];
      half8 bv = bp[(64 + kc * 8 + 0) * 64 + lane];
      half8 bd = bp[(128 + kc * 8 + 0) * 64 + lane];
#pragma unroll
      for (int c = 0; c < 8; ++c) {
        half8 nbu, nbv, nbd;
        if (c < 7) {
          nbu = bp[(kc * 8 + c + 1) * 64 + lane];
          nbv = bp[(64 + kc * 8 + c + 1) * 64 + lane];
          nbd = bp[(128 + kc * 8 + c + 1) * 64 + lane];
        }
#pragma unroll
        for (int r = 0; r < 4; ++r)
          acc[r][c] = __builtin_amdgcn_mfma_f32_16x16x32_f16(u[r], bu, acc[r][c], 0, 0, 0);
#pragma unroll
        for (int r = 0; r < 4; ++r)
          acc[r][c] = __builtin_amdgcn_mfma_f32_16x16x32_f16(v[r], bv, acc[r][c], 0, 0, 0);
#pragma unroll
        for (int r = 0; r < 4; ++r)
          acc[r][c] = __builtin_amdgcn_mfma_f32_16x16x32_f16(d[r], bd, acc[r][c], 0, 0, 0);
        if (c < 7) { bu = nbu; bv = nbv; bd = nbd; }
      }
    }
    // epilogue: D layout col=lane&15, row=quad*4+reg
#pragma unroll
    for (int r = 0; r < 4; ++r) {
      const int erow = w * 64 + r * 16 + quad * 4;
#pragma unroll
      for (int c = 0; c < 8; ++c) {
        const int colL = c * 16 + m15;
        const float wgv = s_wg[colL], c0v = s_c0[colL];
#pragma unroll
        for (int reg = 0; reg < 4; ++reg) {
          const int e = base + erow + reg;
          float x = acc[r][c][reg] + s_g[erow + reg] * wgv + c0v;
          x = fmaxf(x, 0.f);
          if (e >= NE) x = 0.f;
          st_s[c] += x; st_q[c] += x * x;
          if (e < NE) x1[(size_t)e * H1 + colL] = (_Float16)x;
        }
      }
    }
  }
  __syncthreads();
#pragma unroll
  for (int c = 0; c < 8; ++c) {
    float a = st_s[c]; a += __shfl_xor(a, 16); a += __shfl_xor(a, 32);
    float b = st_q[c]; b += __shfl_xor(b, 16); b += __shfl_xor(b, 32);
    if (lane < 16) { atomicAdd(&s_sum[c * 16 + m15], a); atomicAdd(&s_sq[c * 16 + m15], b); }
  }
  __syncthreads();
  if (t < 128) {
    p1[t * GRID1 + bid] = s_sum[t];
    p1[128 * GRID1 + t * GRID1 + bid] = s_sq[t];
  }
}

// Finalize BN1 stats, fold into W2/b2 (fp32 row-major out)
__global__ void k_fin1(const float* __restrict__ p1, const float* __restrict__ g1,
                       const float* __restrict__ be1, const float* __restrict__ W2,
                       const float* __restrict__ b2, float* __restrict__ w2f,
                       float* __restrict__ b2f) {
  __shared__ float s1[128], t1[128];
  const int t = threadIdx.x;
  if (t < 128) {
    float s = 0.f, q = 0.f;
    const float4* rs = (const float4*)(p1 + t * GRID1);
    const float4* rq = (const float4*)(p1 + 128 * GRID1 + t * GRID1);
#pragma unroll 4
    for (int i = 0; i < GRID1 / 4; ++i) {
      float4 a = rs[i]; s += a.x + a.y + a.z + a.w;
      float4 b = rq[i]; q += b.x + b.y + b.z + b.w;
    }
    const float inv = 1.0f / (float)NE;
    float mean = s * inv;
    float var = q * inv - mean * mean;
    float sc = g1[t] * rsqrtf(var + EPSBN);
    s1[t] = sc; t1[t] = be1[t] - mean * sc;
  }
  __syncthreads();
  for (int i = t; i < H1 * H2; i += 256) w2f[i] = s1[i >> 6] * W2[i];
  if (t < 64) {
    float b = b2[t];
    for (int j = 0; j < 128; ++j) b += t1[j] * W2[j * 64 + t];
    b2f[t] = b;
  }
}

// Layer 2 via MFMA: x2 = relu(x1 @ W2F + b2F), B (16KB) resident in LDS
__global__ __launch_bounds__(256, 2)
void k_layer2(const _Float16* __restrict__ x1, const float* __restrict__ w2f,
              const float* __restrict__ b2f, _Float16* __restrict__ x2,
              float* __restrict__ p2) {
  __shared__ __align__(16) _Float16 b_lds[8192];  // 4 ksteps x 4 coltiles frag order
  __shared__ float s_b[64], s_sum[64], s_sq[64];
  const int t = threadIdx.x, bid = blockIdx.x;
  const int w = t >> 6, lane = t & 63, quad = lane >> 4, m15 = lane & 15;

  for (int i = t; i < 8192; i += 256) {
    const int j = i & 7, li = (i >> 3) & 63, f = i >> 9;
    const int c = f & 3, kk = f >> 2;
    const int row = kk * 32 + (li >> 4) * 8 + j;
    const int col = c * 16 + (li & 15);
    b_lds[i] = (_Float16)w2f[row * H2 + col];
  }
  if (t < 64) { s_b[t] = b2f[t]; s_sum[t] = 0.f; s_sq[t] = 0.f; }
  __syncthreads();

  float st_s[4] = {0, 0, 0, 0}, st_q[4] = {0, 0, 0, 0};
  const half8* bp = (const half8*)b_lds;

  for (int job = bid; job < NJOBS2; job += GRID1) {
    const int base = job * 256;
    const _Float16* pa[4];
#pragma unroll
    for (int r = 0; r < 4; ++r) {
      int e = base + w * 64 + r * 16 + m15; if (e >= NE) e = NE - 1;
      pa[r] = x1 + (size_t)e * H1 + quad * 8;
    }
    f32x4 acc[4][4];
#pragma unroll
    for (int r = 0; r < 4; ++r)
#pragma unroll
      for (int c = 0; c < 4; ++c) acc[r][c] = (f32x4)0.f;

#pragma unroll
    for (int kk = 0; kk < 4; ++kk) {
      half8 a[4];
#pragma unroll
      for (int r = 0; r < 4; ++r) a[r] = *(const half8*)(pa[r] + kk * 32);
#pragma unroll
      for (int c = 0; c < 4; ++c) {
        const half8 bf = bp[(kk * 4 + c) * 64 + lane];
#pragma unroll
        for (int r = 0; r < 4; ++r)
          acc[r][c] = __builtin_amdgcn_mfma_f32_16x16x32_f16(a[r], bf, acc[r][c], 0, 0, 0);
      }
    }
#pragma unroll
    for (int r = 0; r < 4; ++r) {
      const int erow = w * 64 + r * 16 + quad * 4;
#pragma unroll
      for (int c = 0; c < 4; ++c) {
        const int colL = c * 16 + m15;
        const float bv = s_b[colL];
#pragma unroll
        for (int reg = 0; reg < 4; ++reg) {
          const int e = base + erow + reg;
          float x = acc[r][c][reg] + bv;
          x = fmaxf(x, 0.f);
          if (e >= NE) x = 0.f;
          st_s[c] += x; st_q[c] += x * x;
          if (e < NE) x2[(size_t)e * H2 + colL] = (_Float16)x;
        }
      }
    }
  }
  __syncthreads();
#pragma unroll
  for (int c = 0; c < 4; ++c) {
    float a = st_s[c]; a += __shfl_xor(a, 16); a += __shfl_xor(a, 32);
    float b = st_q[c]; b += __shfl_xor(b, 16); b += __shfl_xor(b, 32);
    if (lane < 16) { atomicAdd(&s_sum[c * 16 + m15], a); atomicAdd(&s_sq[c * 16 + m15], b); }
  }
  __syncthreads();
  if (t < 64) {
    p2[t * 512 + bid] = s_sum[t];
    p2[64 * 512 + t * 512 + bid] = s_sq[t];
  }
}

// Finalize BN2, fold into W3/b3
__global__ void k_fin2(const float* __restrict__ p2, const float* __restrict__ g2,
                       const float* __restrict__ be2, const float* __restrict__ W3,
                       const float* __restrict__ b3, float* __restrict__ w3f,
                       float* __restrict__ b3f) {
  __shared__ float tp[64];
  const int t = threadIdx.x;
  if (t < 64) {
    float s = 0.f, q = 0.f;
    const float4* rs = (const float4*)(p2 + t * 512);
    const float4* rq = (const float4*)(p2 + 64 * 512 + t * 512);
#pragma unroll 4
    for (int i = 0; i < 128; ++i) {
      float4 a = rs[i]; s += a.x + a.y + a.z + a.w;
      float4 b = rq[i]; q += b.x + b.y + b.z + b.w;
    }
    const float inv = 1.0f / (float)NE;
    float mean = s * inv;
    float var = q * inv - mean * mean;
    float sc = g2[t] * rsqrtf(var + EPSBN);
    float tt = be2[t] - mean * sc;
    w3f[t] = sc * W3[t];
    tp[t] = tt * W3[t];
  }
  __syncthreads();
  if (t == 0) {
    float b = b3[0];
    for (int j = 0; j < 64; ++j) b += tp[j];
    b3f[0] = b;
  }
}

// out = tanh(x2 @ w3f + b3f); 4 lanes per edge
__global__ __launch_bounds__(256)
void k_out(const unsigned short* __restrict__ x2, const float* __restrict__ w3f,
           const float* __restrict__ b3f, float* __restrict__ out) {
  __shared__ float s_w[64];
  __shared__ float s_b;
  const int t = threadIdx.x;
  if (t < 64) s_w[t] = w3f[t];
  if (t == 0) s_b = b3f[0];
  __syncthreads();
  const int gid = blockIdx.x * 256 + t;
  const int e = gid >> 2, p = gid & 3;
  if (e < NE) {
    const uint4* r = (const uint4*)(x2 + (size_t)e * H2 + p * 16);
    float s = 0.f;
#pragma unroll
    for (int i = 0; i < 2; ++i) {
      const uint4 u = r[i];
      const int jb = p * 16 + i * 8;
      s += h2f(u.x) * s_w[jb + 0] + h2f(u.x >> 16) * s_w[jb + 1];
      s += h2f(u.y) * s_w[jb + 2] + h2f(u.y >> 16) * s_w[jb + 3];
      s += h2f(u.z) * s_w[jb + 4] + h2f(u.z >> 16) * s_w[jb + 5];
      s += h2f(u.w) * s_w[jb + 6] + h2f(u.w >> 16) * s_w[jb + 7];
    }
    s += __shfl_xor(s, 1);
    s += __shfl_xor(s, 2);
    if (p == 0) out[e] = tanhf(s + s_b);
  }
}

extern "C" void kernel_launch(void* const* d_in, const int* in_sizes, int n_in,
                              void* d_out, int out_size, void* d_ws, size_t ws_size,
                              hipStream_t stream) {
  const float* emb  = (const float*)d_in[0];
  const float* grad = (const float*)d_in[1];
  const float* step = (const float*)d_in[2];
  const float* W1   = (const float*)d_in[3];
  const float* b1   = (const float*)d_in[4];
  const float* g1   = (const float*)d_in[5];
  const float* be1  = (const float*)d_in[6];
  const float* W2   = (const float*)d_in[7];
  const float* b2   = (const float*)d_in[8];
  const float* g2   = (const float*)d_in[9];
  const float* be2  = (const float*)d_in[10];
  const float* W3   = (const float*)d_in[11];
  const float* b3   = (const float*)d_in[12];
  const void*  eidx = (const void*)d_in[13];
  float* out = (float*)d_out;

  char* ws = (char*)d_ws;
  // region A (64MB): embh (25.6MB) + bfrag + c0 during layer1; x2 overwrites in layer2
  _Float16* embh  = (_Float16*)(ws + 0);
  _Float16* x2    = (_Float16*)(ws + 0);
  _Float16* bfrag = (_Float16*)(ws + 25600000LL);  // 196,608 B (clobbered by x2 later)
  float*    c0    = (float*)(ws + 25796608LL);     // 512 B     (clobbered by x2 later)
  _Float16* x1    = (_Float16*)(ws + 64000000LL);  // 128,000,000 B
  float* p1  = (float*)(ws + 192000000LL);         // 524,288 B (128 sums + 128 sqs x 512)
  float* p2  = (float*)(ws + 192524288LL);         // 262,144 B
  float* w2f = (float*)(ws + 192786432LL);         // 32,768 B
  float* b2f = (float*)(ws + 192819200LL);         // 256 B
  float* w3f = (float*)(ws + 192819456LL);         // 256 B
  float* b3f = (float*)(ws + 192819712LL);         // 16 B  -> end 192,819,728

  k_prep  <<<1,    256, 0, stream>>>(W1, b1, step, c0);
  k_prep16<<<6250, 256, 0, stream>>>(emb, embh);
  k_prepB <<<48,   256, 0, stream>>>(W1, bfrag);
  k_layer1<<<GRID1,256, 0, stream>>>(embh, eidx, grad, W1, c0, bfrag, x1, p1);
  k_fin1  <<<1,    256, 0, stream>>>(p1, g1, be1, W2, b2, w2f, b2f);
  k_layer2<<<GRID1,256, 0, stream>>>(x1, w2f, b2f, x2, p2);
  k_fin2  <<<1,    128, 0, stream>>>(p2, g2, be2, W3, b3, w3f, b3f);
  k_out   <<<7813, 256, 0, stream>>>((const unsigned short*)x2, w3f, b3f, out);
}